// Round 1
// baseline (1077.782 us; speedup 1.0000x reference)
//
#include <hip/hip_runtime.h>

#define DIM 128

// ---------------- graph preprocessing ----------------

__global__ __launch_bounds__(256) void k_count(const int* __restrict__ dst,
                                               int* __restrict__ cnt, int E) {
    int e = blockIdx.x * 256 + threadIdx.x;
    if (e < E) atomicAdd(&cnt[dst[e]], 1);
}

// single-block exclusive scan over cnt[n]; writes offs[0..n], rewrites cnt[] as
// cursor (== offs[i]), and dinv[i] = rsqrt(cnt+1)
__global__ __launch_bounds__(1024) void k_scan(int* __restrict__ cnt,
                                               int* __restrict__ offs,
                                               float* __restrict__ dinv, int n) {
    __shared__ int sums[1024];
    int t = threadIdx.x;
    int CH = (n + 1023) / 1024;
    int lo = t * CH, hi = lo + CH;
    if (hi > n) hi = n;
    int s = 0;
    for (int i = lo; i < hi; ++i) s += cnt[i];
    sums[t] = s;
    __syncthreads();
    // inclusive Hillis-Steele scan
    for (int off = 1; off < 1024; off <<= 1) {
        int u = (t >= off) ? sums[t - off] : 0;
        __syncthreads();
        sums[t] += u;
        __syncthreads();
    }
    int run = (t == 0) ? 0 : sums[t - 1];
    for (int i = lo; i < hi; ++i) {
        int c = cnt[i];
        offs[i] = run;
        cnt[i]  = run;                       // cursor init
        dinv[i] = rsqrtf((float)(c + 1));    // +1 self-loop
        run += c;
    }
    if (t == 1023) offs[n] = run;
}

__global__ __launch_bounds__(256) void k_fill(const int* __restrict__ src,
                                              const int* __restrict__ dst,
                                              int* __restrict__ curs,
                                              int* __restrict__ csrc, int E) {
    int e = blockIdx.x * 256 + threadIdx.x;
    if (e < E) {
        int p = atomicAdd(&curs[dst[e]], 1);
        csrc[p] = src[e];
    }
}

// ---------------- GEMM: out[r] = dinv[r] * (in[r] @ W), W is [DIM][DIM] ----------------
// block: 256 threads; 128 rows/block; thread = (row-slot rs = t>>2) x (dim group g = t&3, 32 dims)
// each thread: 2 rows (rs, rs+64) x 32 dims, accumulators statically indexed.

__global__ __launch_bounds__(256) void k_gemm(const float* __restrict__ in,
                                              const float* __restrict__ W,
                                              const float* __restrict__ dinv,
                                              float* __restrict__ out, int n) {
    __shared__ float Wl[DIM * DIM];  // 64 KB
    int t = threadIdx.x;
    {   // cooperative load of W (row-major [k][d]) as float4
        const float4* W4 = (const float4*)W;
        float4* Wl4 = (float4*)Wl;
#pragma unroll
        for (int i = 0; i < 16; ++i) Wl4[t + i * 256] = W4[t + i * 256];
    }
    __syncthreads();

    int g  = t & 3;        // dims [g*32, g*32+32)
    int rs = t >> 2;       // 0..63
    int base = blockIdx.x * 128;
    int r0 = base + rs, r1 = base + rs + 64;
    int rr0 = (r0 < n) ? r0 : (n - 1);
    int rr1 = (r1 < n) ? r1 : (n - 1);

    float acc0[32], acc1[32];
#pragma unroll
    for (int j = 0; j < 32; ++j) { acc0[j] = 0.f; acc1[j] = 0.f; }

    const float* p0 = in + (size_t)rr0 * DIM;
    const float* p1 = in + (size_t)rr1 * DIM;

#pragma unroll 2
    for (int k = 0; k < DIM; ++k) {
        float a0 = p0[k];
        float a1 = p1[k];
#pragma unroll
        for (int jj = 0; jj < 8; ++jj) {
            int q = (jj + 2 * g) & 7;  // staggered quad -> conflict-free banks
            float4 w = *(const float4*)&Wl[k * DIM + g * 32 + q * 4];
            acc0[jj * 4 + 0] += a0 * w.x;
            acc0[jj * 4 + 1] += a0 * w.y;
            acc0[jj * 4 + 2] += a0 * w.z;
            acc0[jj * 4 + 3] += a0 * w.w;
            acc1[jj * 4 + 0] += a1 * w.x;
            acc1[jj * 4 + 1] += a1 * w.y;
            acc1[jj * 4 + 2] += a1 * w.z;
            acc1[jj * 4 + 3] += a1 * w.w;
        }
    }

    float s0 = dinv[rr0], s1 = dinv[rr1];
    if (r0 < n) {
        float4* o = (float4*)(out + (size_t)r0 * DIM + g * 32);
#pragma unroll
        for (int jj = 0; jj < 8; ++jj) {
            int q = (jj + 2 * g) & 7;
            o[q] = make_float4(acc0[jj * 4 + 0] * s0, acc0[jj * 4 + 1] * s0,
                               acc0[jj * 4 + 2] * s0, acc0[jj * 4 + 3] * s0);
        }
    }
    if (r1 < n) {
        float4* o = (float4*)(out + (size_t)r1 * DIM + g * 32);
#pragma unroll
        for (int jj = 0; jj < 8; ++jj) {
            int q = (jj + 2 * g) & 7;
            o[q] = make_float4(acc1[jj * 4 + 0] * s1, acc1[jj * 4 + 1] * s1,
                               acc1[jj * 4 + 2] * s1, acc1[jj * 4 + 3] * s1);
        }
    }
}

// ---------------- aggregation: out[i] = f(dinv[i]*(H[i] + sum_{e->i} H[src]) + bias) ----------------
// MODE 0: relu -> out ; MODE 1: relu + identity -> out ; MODE 2: plain -> out

template <int MODE>
__global__ __launch_bounds__(128) void k_agg(const float* __restrict__ H,
                                             const float* __restrict__ dinv,
                                             const int* __restrict__ offs,
                                             const int* __restrict__ csrc,
                                             const float* __restrict__ bias,
                                             const float* __restrict__ identity,
                                             float* __restrict__ out) {
    int i = blockIdx.x;
    int d = threadIdx.x;
    float acc = H[(size_t)i * DIM + d];  // self loop
    int s = offs[i], e = offs[i + 1];
    int j = s;
    for (; j + 4 <= e; j += 4) {
        int s0 = csrc[j], s1 = csrc[j + 1], s2 = csrc[j + 2], s3 = csrc[j + 3];
        float v0 = H[(size_t)s0 * DIM + d];
        float v1 = H[(size_t)s1 * DIM + d];
        float v2 = H[(size_t)s2 * DIM + d];
        float v3 = H[(size_t)s3 * DIM + d];
        acc += v0; acc += v1; acc += v2; acc += v3;
    }
    for (; j < e; ++j) acc += H[(size_t)csrc[j] * DIM + d];
    float v = dinv[i] * acc + bias[d];
    if (MODE == 0) out[(size_t)i * DIM + d] = fmaxf(v, 0.f);
    if (MODE == 1) out[(size_t)i * DIM + d] = fmaxf(v, 0.f) + identity[(size_t)i * DIM + d];
    if (MODE == 2) out[(size_t)i * DIM + d] = v;
}

// ---------------- LayerNorm over last dim (128), one wave per row ----------------

__global__ __launch_bounds__(256) void k_ln(const float* __restrict__ in,
                                            const float* __restrict__ g,
                                            const float* __restrict__ b,
                                            float* __restrict__ out, int n) {
    int w = threadIdx.x >> 6, lane = threadIdx.x & 63;
    int row = blockIdx.x * 4 + w;
    if (row >= n) return;
    float2 v = ((const float2*)(in + (size_t)row * DIM))[lane];
    float s = v.x + v.y;
#pragma unroll
    for (int m = 1; m < 64; m <<= 1) s += __shfl_xor(s, m);
    float mu = s * (1.f / 128.f);
    float dx = v.x - mu, dy = v.y - mu;
    float q = dx * dx + dy * dy;
#pragma unroll
    for (int m = 1; m < 64; m <<= 1) q += __shfl_xor(q, m);
    float rstd = rsqrtf(q * (1.f / 128.f) + 1e-5f);
    float2 gg = ((const float2*)g)[lane];
    float2 bb = ((const float2*)b)[lane];
    float2 o;
    o.x = dx * rstd * gg.x + bb.x;
    o.y = dy * rstd * gg.y + bb.y;
    ((float2*)(out + (size_t)row * DIM))[lane] = o;
}

// ---------------- launch ----------------

extern "C" void kernel_launch(void* const* d_in, const int* in_sizes, int n_in,
                              void* d_out, int out_size, void* d_ws, size_t ws_size,
                              hipStream_t stream) {
    const float* x   = (const float*)d_in[0];
    const int*   ei  = (const int*)d_in[1];
    const float* W0  = (const float*)d_in[2];
    const float* b0  = (const float*)d_in[3];
    const float* W1  = (const float*)d_in[4];
    const float* b1  = (const float*)d_in[5];
    const float* W2  = (const float*)d_in[6];
    const float* b2  = (const float*)d_in[7];
    const float* lng = (const float*)d_in[8];
    const float* lnb = (const float*)d_in[9];
    const float* fng = (const float*)d_in[10];
    const float* fnb = (const float*)d_in[11];
    float* out = (float*)d_out;

    int n = in_sizes[0] / DIM;       // 100000
    int E = in_sizes[1] / 2;         // 1600000
    const int* src = ei;
    const int* dst = ei + E;

    size_t ND = (size_t)n * DIM;
    float* ws   = (float*)d_ws;
    float* H    = ws;                 // [n*DIM] GEMM output (pre-scaled by dinv)
    float* hb   = ws + ND;            // [n*DIM] layer state / identity
    float* dinv = ws + 2 * ND;        // [n]
    int*   offs = (int*)(dinv + n);   // [n+1]
    int*   cnt  = offs + (n + 1);     // [n]  counts -> cursor
    int*   csrc = cnt + n;            // [E]

    dim3 blk256(256), blk128(128), blk1024(1024);
    int grid_e = (E + 255) / 256;
    int grid_g = (n + 127) / 128;

    hipMemsetAsync(cnt, 0, (size_t)n * sizeof(int), stream);
    k_count<<<grid_e, blk256, 0, stream>>>(dst, cnt, E);
    k_scan<<<1, blk1024, 0, stream>>>(cnt, offs, dinv, n);
    k_fill<<<grid_e, blk256, 0, stream>>>(src, dst, cnt, csrc, E);

    // layer 0: h = relu(conv(x, W0, b0))
    k_gemm<<<grid_g, blk256, 0, stream>>>(x, W0, dinv, H, n);
    k_agg<0><<<n, blk128, 0, stream>>>(H, dinv, offs, csrc, b0, nullptr, hb);

    // middle block: identity=hb; hn = LN(hb); hb = relu(conv(hn,W1,b1)) + identity
    k_ln<<<(n + 3) / 4, blk256, 0, stream>>>(hb, lng, lnb, out, n);
    k_gemm<<<grid_g, blk256, 0, stream>>>(out, W1, dinv, H, n);
    k_agg<1><<<n, blk128, 0, stream>>>(H, dinv, offs, csrc, b1, hb, hb);

    // final: out = LN(conv(hb, W2, b2))
    k_gemm<<<grid_g, blk256, 0, stream>>>(hb, W2, dinv, H, n);
    k_agg<2><<<n, blk128, 0, stream>>>(H, dinv, offs, csrc, b2, nullptr, out);
    k_ln<<<(n + 3) / 4, blk256, 0, stream>>>(out, fng, fnb, out, n);
}

// Round 2
// 794.102 us; speedup vs baseline: 1.3572x; 1.3572x over previous
//
#include <hip/hip_runtime.h>

#define DIM 128
#define SB 256  // scan block size

// ---------------- graph preprocessing ----------------

__global__ __launch_bounds__(256) void k_count(const int* __restrict__ dst,
                                               int* __restrict__ cnt, int E) {
    int e = blockIdx.x * 256 + threadIdx.x;
    if (e < E) atomicAdd(&cnt[dst[e]], 1);
}

// phase 1: per-block sums of cnt
__global__ __launch_bounds__(SB) void k_scan1(const int* __restrict__ cnt,
                                              int* __restrict__ bsum, int n) {
    int t = threadIdx.x;
    int i = blockIdx.x * SB + t;
    int v = (i < n) ? cnt[i] : 0;
#pragma unroll
    for (int m = 1; m < 64; m <<= 1) v += __shfl_xor(v, m);
    __shared__ int w[SB / 64];
    if ((t & 63) == 0) w[t >> 6] = v;
    __syncthreads();
    if (t == 0) {
        int s = 0;
#pragma unroll
        for (int k = 0; k < SB / 64; ++k) s += w[k];
        bsum[blockIdx.x] = s;
    }
}

// phase 2: exclusive scan of block sums (B <= 1024), in place
__global__ __launch_bounds__(1024) void k_scan2(int* __restrict__ bsum, int B) {
    __shared__ int s[1024];
    int t = threadIdx.x;
    int v = (t < B) ? bsum[t] : 0;
    s[t] = v;
    __syncthreads();
    for (int off = 1; off < 1024; off <<= 1) {
        int u = (t >= off) ? s[t - off] : 0;
        __syncthreads();
        s[t] += u;
        __syncthreads();
    }
    if (t < B) bsum[t] = s[t] - v;  // exclusive
}

// phase 3: local scan + block offset -> offs, cursor, dinv
__global__ __launch_bounds__(SB) void k_scan3(int* __restrict__ cnt,
                                              const int* __restrict__ bsum,
                                              int* __restrict__ offs,
                                              float* __restrict__ dinv, int n) {
    __shared__ int s[SB];
    int t = threadIdx.x;
    int i = blockIdx.x * SB + t;
    int c = (i < n) ? cnt[i] : 0;
    s[t] = c;
    __syncthreads();
    for (int off = 1; off < SB; off <<= 1) {
        int u = (t >= off) ? s[t - off] : 0;
        __syncthreads();
        s[t] += u;
        __syncthreads();
    }
    int excl = bsum[blockIdx.x] + s[t] - c;
    if (i < n) {
        offs[i] = excl;
        cnt[i]  = excl;                      // cursor init
        dinv[i] = rsqrtf((float)(c + 1));    // +1 self-loop
        if (i == n - 1) offs[n] = excl + c;
    }
}

__global__ __launch_bounds__(256) void k_fill(const int* __restrict__ src,
                                              const int* __restrict__ dst,
                                              int* __restrict__ curs,
                                              int* __restrict__ csrc, int E) {
    int e = blockIdx.x * 256 + threadIdx.x;
    if (e < E) {
        int p = atomicAdd(&curs[dst[e]], 1);
        csrc[p] = src[e];
    }
}

// ---------------- GEMM: out[r] = dinv[r] * (in[r] @ W) ----------------

__global__ __launch_bounds__(256) void k_gemm(const float* __restrict__ in,
                                              const float* __restrict__ W,
                                              const float* __restrict__ dinv,
                                              float* __restrict__ out, int n) {
    __shared__ float Wl[DIM * DIM];  // 64 KB
    int t = threadIdx.x;
    {
        const float4* W4 = (const float4*)W;
        float4* Wl4 = (float4*)Wl;
#pragma unroll
        for (int i = 0; i < 16; ++i) Wl4[t + i * 256] = W4[t + i * 256];
    }
    __syncthreads();

    int g  = t & 3;
    int rs = t >> 2;
    int base = blockIdx.x * 128;
    int r0 = base + rs, r1 = base + rs + 64;
    int rr0 = (r0 < n) ? r0 : (n - 1);
    int rr1 = (r1 < n) ? r1 : (n - 1);

    float acc0[32], acc1[32];
#pragma unroll
    for (int j = 0; j < 32; ++j) { acc0[j] = 0.f; acc1[j] = 0.f; }

    const float* p0 = in + (size_t)rr0 * DIM;
    const float* p1 = in + (size_t)rr1 * DIM;

#pragma unroll 2
    for (int k = 0; k < DIM; ++k) {
        float a0 = p0[k];
        float a1 = p1[k];
#pragma unroll
        for (int jj = 0; jj < 8; ++jj) {
            int q = (jj + 2 * g) & 7;
            float4 w = *(const float4*)&Wl[k * DIM + g * 32 + q * 4];
            acc0[jj * 4 + 0] += a0 * w.x;
            acc0[jj * 4 + 1] += a0 * w.y;
            acc0[jj * 4 + 2] += a0 * w.z;
            acc0[jj * 4 + 3] += a0 * w.w;
            acc1[jj * 4 + 0] += a1 * w.x;
            acc1[jj * 4 + 1] += a1 * w.y;
            acc1[jj * 4 + 2] += a1 * w.z;
            acc1[jj * 4 + 3] += a1 * w.w;
        }
    }

    float s0 = dinv[rr0], s1 = dinv[rr1];
    if (r0 < n) {
        float4* o = (float4*)(out + (size_t)r0 * DIM + g * 32);
#pragma unroll
        for (int jj = 0; jj < 8; ++jj) {
            int q = (jj + 2 * g) & 7;
            o[q] = make_float4(acc0[jj * 4 + 0] * s0, acc0[jj * 4 + 1] * s0,
                               acc0[jj * 4 + 2] * s0, acc0[jj * 4 + 3] * s0);
        }
    }
    if (r1 < n) {
        float4* o = (float4*)(out + (size_t)r1 * DIM + g * 32);
#pragma unroll
        for (int jj = 0; jj < 8; ++jj) {
            int q = (jj + 2 * g) & 7;
            o[q] = make_float4(acc1[jj * 4 + 0] * s1, acc1[jj * 4 + 1] * s1,
                               acc1[jj * 4 + 2] * s1, acc1[jj * 4 + 3] * s1);
        }
    }
}

// ---------------- aggregation + optional fused LayerNorm ----------------
// raw = MODE0: relu(v)  MODE1: relu(v)+identity  MODE2: v
// MODE 0: write raw -> out_raw, write LN(raw) -> out_ln
// MODE 1: write raw -> out_raw
// MODE 2: write LN(raw) -> out_ln (no raw write)

template <int MODE>
__global__ __launch_bounds__(128) void k_agg(const float* __restrict__ H,
                                             const float* __restrict__ dinv,
                                             const int* __restrict__ offs,
                                             const int* __restrict__ csrc,
                                             const float* __restrict__ bias,
                                             const float* __restrict__ identity,
                                             float* __restrict__ out_raw,
                                             float* __restrict__ out_ln,
                                             const float* __restrict__ lg,
                                             const float* __restrict__ lb) {
    int i = blockIdx.x;
    int d = threadIdx.x;
    float acc = H[(size_t)i * DIM + d];  // self loop
    int s = offs[i], e = offs[i + 1];
    int j = s;
    for (; j + 4 <= e; j += 4) {
        int s0 = csrc[j], s1 = csrc[j + 1], s2 = csrc[j + 2], s3 = csrc[j + 3];
        acc += H[(size_t)s0 * DIM + d];
        acc += H[(size_t)s1 * DIM + d];
        acc += H[(size_t)s2 * DIM + d];
        acc += H[(size_t)s3 * DIM + d];
    }
    for (; j < e; ++j) acc += H[(size_t)csrc[j] * DIM + d];
    float v = dinv[i] * acc + bias[d];

    float x;
    if (MODE == 0) x = fmaxf(v, 0.f);
    if (MODE == 1) x = fmaxf(v, 0.f) + identity[(size_t)i * DIM + d];
    if (MODE == 2) x = v;

    if (MODE == 0 || MODE == 1) out_raw[(size_t)i * DIM + d] = x;

    if (MODE == 0 || MODE == 2) {
        // fused LayerNorm over the 128 dims held by this block (2 waves)
        __shared__ float red[4];
        int wv = d >> 6;
        float su = x;
#pragma unroll
        for (int m = 1; m < 64; m <<= 1) su += __shfl_xor(su, m);
        if ((d & 63) == 0) red[wv] = su;
        __syncthreads();
        float mu = (red[0] + red[1]) * (1.f / 128.f);
        float dx = x - mu;
        float q = dx * dx;
#pragma unroll
        for (int m = 1; m < 64; m <<= 1) q += __shfl_xor(q, m);
        if ((d & 63) == 0) red[2 + wv] = q;
        __syncthreads();
        float rstd = rsqrtf((red[2] + red[3]) * (1.f / 128.f) + 1e-5f);
        out_ln[(size_t)i * DIM + d] = dx * rstd * lg[d] + lb[d];
    }
}

// ---------------- launch ----------------

extern "C" void kernel_launch(void* const* d_in, const int* in_sizes, int n_in,
                              void* d_out, int out_size, void* d_ws, size_t ws_size,
                              hipStream_t stream) {
    const float* x   = (const float*)d_in[0];
    const int*   ei  = (const int*)d_in[1];
    const float* W0  = (const float*)d_in[2];
    const float* b0  = (const float*)d_in[3];
    const float* W1  = (const float*)d_in[4];
    const float* b1  = (const float*)d_in[5];
    const float* W2  = (const float*)d_in[6];
    const float* b2  = (const float*)d_in[7];
    const float* lng = (const float*)d_in[8];
    const float* lnb = (const float*)d_in[9];
    const float* fng = (const float*)d_in[10];
    const float* fnb = (const float*)d_in[11];
    float* out = (float*)d_out;

    int n = in_sizes[0] / DIM;       // 100000
    int E = in_sizes[1] / 2;         // 1600000
    const int* src = ei;
    const int* dst = ei + E;

    size_t ND = (size_t)n * DIM;
    float* ws   = (float*)d_ws;
    float* H    = ws;                 // [n*DIM] GEMM output (pre-scaled by dinv)
    float* hb   = ws + ND;            // [n*DIM] layer state / identity
    float* dinv = ws + 2 * ND;        // [n]
    int*   offs = (int*)(dinv + n);   // [n+1]
    int*   cnt  = offs + (n + 1);     // [n]  counts -> cursor
    int*   bsum = cnt + n;            // [<=1024] scan block sums
    int*   csrc = bsum + 1024;        // [E]

    int grid_e = (E + 255) / 256;
    int grid_g = (n + 127) / 128;
    int B = (n + SB - 1) / SB;        // scan blocks (391)

    hipMemsetAsync(cnt, 0, (size_t)n * sizeof(int), stream);
    k_count<<<grid_e, 256, 0, stream>>>(dst, cnt, E);
    k_scan1<<<B, SB, 0, stream>>>(cnt, bsum, n);
    k_scan2<<<1, 1024, 0, stream>>>(bsum, B);
    k_scan3<<<B, SB, 0, stream>>>(cnt, bsum, offs, dinv, n);
    k_fill<<<grid_e, 256, 0, stream>>>(src, dst, cnt, csrc, E);

    // layer 0: hb = relu(conv(x)); out(temp) = LN(hb)
    k_gemm<<<grid_g, 256, 0, stream>>>(x, W0, dinv, H, n);
    k_agg<0><<<n, 128, 0, stream>>>(H, dinv, offs, csrc, b0, nullptr, hb, out, lng, lnb);

    // middle: hb = relu(conv(LN)) + hb
    k_gemm<<<grid_g, 256, 0, stream>>>(out, W1, dinv, H, n);
    k_agg<1><<<n, 128, 0, stream>>>(H, dinv, offs, csrc, b1, hb, hb, nullptr, nullptr, nullptr);

    // final: out = LN(conv(hb))
    k_gemm<<<grid_g, 256, 0, stream>>>(hb, W2, dinv, H, n);
    k_agg<2><<<n, 128, 0, stream>>>(H, dinv, offs, csrc, b2, nullptr, nullptr, out, fng, fnb);
}